// Round 11
// baseline (50476.663 us; speedup 1.0000x reference)
//
#include <hip/hip_runtime.h>
#include <hip/hip_bf16.h>
#include <math.h>

// WaveNet autoregressive generation, MI355X, fp32 (argmax feedback forbids
// low precision; no fp32 MFMA on CDNA4 -> vector ALU kernel).
//
// One WG of 320 threads (5 waves) per batch element; latency-bound on the
// per-element serial chain. R10 (12.57 ms, passed) + this round's changes:
//  - LDS-only barriers: `s_waitcnt lgkmcnt(0); s_barrier` instead of
//    __syncthreads() (which drains vmcnt(0) and would kill prefetch).
//    AUDIT: no cross-thread global dependency crosses any barrier — queue
//    slots are written and re-read by the SAME wave-4 thread >=1 step
//    (~100K cy) apart; logits/samples are host-read only. LDS (hp, xbuf,
//    sxl, sskip, sh0, snext) is ordered by lgkmcnt(0).
//  - Register weight prefetch, compute-then-issue, single buffer: each
//    thread's next-phase weight column (64 floats) is issued right after the
//    current dot consumes the buffer, and stays in flight ACROSS the barrier
//    into the next phase (~1 full phase of cover >= L2/L3 latency).
//    Weights are step-invariant: at layer 29 the prefetch wraps to layer 0
//    for the next step, covered by the whole output head.
//  - Per-lane LDS read + v_readlane broadcast replaces 64 uniform-address
//    ds_reads per dot (and 256 in each head matmul).
//  - cbias/skipb/resb prefetched one layer ahead into registers.

#define NL 30
#define NC 64
#define NS 256
#define NV 256
#define NB 128
#define QTOT 3069   // sum of dilations: 3 * (2^10 - 1)
#define NT 320

// Per-batch dilation queues (~100.6 MB) in static device memory. Slot for
// layer l is written at step t and read at step t+d; reads gated by (t >= d)
// so stale cross-launch contents are never observed (re-poison safe).
__device__ float g_queues[(size_t)NB * QTOT * NC];

__device__ __forceinline__ void layer_params(int l, int& d, int& qo) {
  const int a = (l >= 20) ? 2 : ((l >= 10) ? 1 : 0);
  const int bb = l - a * 10;
  d = 1 << bb;
  qo = a * 1023 + (d - 1);
}

// tanh(a)*sigmoid(b) = (e^{2a}-1) / ((e^{2a}+1)*(1+e^{-b}))
__device__ __forceinline__ float gate_fast(float ha, float hb) {
  const float e2a = __expf(2.f * ha);
  const float enb = __expf(-hb);
  return (e2a - 1.f) / ((e2a + 1.f) * (1.f + enb));
}

// broadcast lane c's value across the wave (v_readlane -> SGPR operand)
__device__ __forceinline__ float bcast(float v, int c) {
  return __uint_as_float(__builtin_amdgcn_readlane(__float_as_uint(v), (unsigned)c));
}

// LDS-only barrier: orders LDS, leaves global loads/stores in flight.
__device__ __forceinline__ void wg_barrier() {
  asm volatile("s_waitcnt lgkmcnt(0)" ::: "memory");
  __builtin_amdgcn_s_barrier();
}

__global__ __launch_bounds__(NT, 1)
void wavenet_gen_kernel(const int* __restrict__ seed,
                        const float* __restrict__ emb,     // (V, C)
                        const float* __restrict__ kern,    // (L, 2, C, 2C)
                        const float* __restrict__ cbias,   // (L, 2C)
                        const float* __restrict__ resw,    // (L, C, C)
                        const float* __restrict__ resb,    // (L, C)
                        const float* __restrict__ skipw,   // (L, C, S)
                        const float* __restrict__ skipb,   // (L, S)
                        const float* __restrict__ w0,      // (S, V)
                        const float* __restrict__ b0,      // (V)
                        const float* __restrict__ w1,      // (V, V)
                        const float* __restrict__ b1,      // (V)
                        const int* __restrict__ pT,
                        float* __restrict__ out)
{
  const int b    = blockIdx.x;
  const int t_   = threadIdx.x;
  const int T    = pT[0];
  const int lane = t_ & 63;
  const int w    = t_ >> 6;                    // wave 0..4
  const int half = w & 1;                      // conv: x_last (0) vs x (1)
  const int colA = ((w >> 1) << 6) + lane;     // conv output col 0..127

  __shared__ float xbuf[2][NC];      // layer input x (double-buffered)
  __shared__ float sxl[2][NC];       // popped x_last (double-buffered)
  __shared__ float hp[2][2 * NC];    // conv partials [half][col]
  __shared__ float sskip[NS];
  __shared__ float sh0[NV];
  __shared__ float rv[4];
  __shared__ int   ri[4];
  __shared__ int   snext;

  // ---- register weight buffers (compile-time indexed only) ----
  float wk[NC];   // waves 0-3: kern column   (wave 4: unused)
  float ws[NC];   // waves 0-3: skipw column; wave 4: resw column
  float rsb;      // waves 0-3: skipb(i); wave 4: resb(i)
  float rca, rcb; // cbias pair for current layer
  float rP0 = 0.f, rP1 = 0.f;        // in-flight queue pops (wave 4)

  if (t_ < NC) {
    sxl[0][t_] = 0.f;                // step-0 pops are zero (t=0 < d)
    sxl[1][t_] = 0.f;
    xbuf[0][t_] = emb[(size_t)seed[b] * NC + t_];
  }
  // prologue prefetch: layer-0 weights + biases
  if (w < 4) {
    const float* __restrict__ Wk = kern + (size_t)half * (NC * 2 * NC) + colA;
#pragma unroll
    for (int c = 0; c < NC; ++c) wk[c] = Wk[(size_t)c * (2 * NC)];
    const float* __restrict__ Ws = skipw + t_;
#pragma unroll
    for (int c = 0; c < NC; ++c) ws[c] = Ws[(size_t)c * NS];
    rsb = skipb[t_];
  } else {
    const float* __restrict__ Wr = resw + lane;
#pragma unroll
    for (int c = 0; c < NC; ++c) ws[c] = Wr[(size_t)c * NC];
    rsb = resb[lane];
  }
  rca = cbias[lane];
  rcb = cbias[NC + lane];
  wg_barrier();

  float* __restrict__ q = g_queues + (size_t)b * QTOT * NC;
  const size_t logits_base = (size_t)NB * (size_t)T;

  for (int t = 0; t < T; ++t) {
    float skipacc = 0.f;             // waves 0..3: skip col t_ accumulator

    for (int i = 0; i < NL; ++i) {
      const int cb = i & 1;
      const int nx = (i + 1 < NL) ? i + 1 : 0;   // next matrix (wraps)

      // ------- phase A: conv (waves 0-3) | queue push/pop (wave 4) -------
      if (w < 4) {
        const float xr = half ? xbuf[cb][lane] : sxl[cb][lane];
        float a0 = 0.f, a1 = 0.f;
#pragma unroll
        for (int c = 0; c < NC; c += 2) {
          a0 = fmaf(bcast(xr, c),     wk[c],     a0);
          a1 = fmaf(bcast(xr, c + 1), wk[c + 1], a1);
        }
        hp[half][colA] = a0 + a1;
        // issue next conv weights; stays in flight across the barrier
        const float* __restrict__ Wk =
            kern + (size_t)(nx * 2 + half) * (NC * 2 * NC) + colA;
#pragma unroll
        for (int c = 0; c < NC; ++c) wk[c] = Wk[(size_t)c * (2 * NC)];
      } else {
        int d, qo; layer_params(i, d, qo);
        q[(size_t)(qo + (t & (d - 1))) * NC + lane] = xbuf[cb][lane];
        const int j = i + 2;                     // pop 2 layers ahead
        if (j < NL) {
          int dj, qj; layer_params(j, dj, qj);
          float v = 0.f;
          if (t >= dj) v = q[(size_t)(qj + (t & (dj - 1))) * NC + lane];
          if (cb) rP1 = v; else rP0 = v;         // j&1 == i&1
        }
      }
      wg_barrier();

      // ------- phase B: gate (all waves) + skip | res + commit pop -------
      const float ha = hp[0][lane] + hp[1][lane] + rca;
      const float hb = hp[0][NC + lane] + hp[1][NC + lane] + rcb;
      const float sgv = gate_fast(ha, hb);       // lane c holds sg[c]
      rca = cbias[nx * 2 * NC + lane];           // prefetch next cbias
      rcb = cbias[nx * 2 * NC + NC + lane];

      if (w < 4) {
        float a0 = 0.f, a1 = 0.f;
#pragma unroll
        for (int c = 0; c < NC; c += 2) {
          a0 = fmaf(bcast(sgv, c),     ws[c],     a0);
          a1 = fmaf(bcast(sgv, c + 1), ws[c + 1], a1);
        }
        skipacc += a0 + a1 + rsb;
        // issue next skip weights + bias
        const float* __restrict__ Ws = skipw + (size_t)nx * NC * NS + t_;
#pragma unroll
        for (int c = 0; c < NC; ++c) ws[c] = Ws[(size_t)c * NS];
        rsb = skipb[nx * NS + t_];
      } else {
        if (i < NL - 1) {                        // layer 29's x is dead
          float a0 = 0.f, a1 = 0.f;
#pragma unroll
          for (int c = 0; c < NC; c += 2) {
            a0 = fmaf(bcast(sgv, c),     ws[c],     a0);
            a1 = fmaf(bcast(sgv, c + 1), ws[c + 1], a1);
          }
          xbuf[cb ^ 1][lane] = xbuf[cb][lane] + a0 + a1 + rsb;
          sxl[cb ^ 1][lane] = (cb ^ 1) ? rP1 : rP0;  // commit pop(i+1)
        }
        const int rnx = (i + 1 < NL - 1) ? i + 1 : 0;  // res cycles 0..28
        const float* __restrict__ Wr = resw + (size_t)rnx * NC * NC + lane;
#pragma unroll
        for (int c = 0; c < NC; ++c) ws[c] = Wr[(size_t)c * NC];
        rsb = resb[rnx * NC + lane];
      }
      wg_barrier();
    }

    // ======================= output head =======================
    // H1: finalize skip | wave 4: issue pops for (t+1, layers 0 and 1)
    if (t_ < NS) {
      sskip[t_] = fmaxf(skipacc, 0.f);
    } else {
      { int d, qo; layer_params(0, d, qo);
        rP0 = (t + 1 >= d) ? q[(size_t)(qo + ((t + 1) & (d - 1))) * NC + lane] : 0.f; }
      { int d, qo; layer_params(1, d, qo);
        rP1 = (t + 1 >= d) ? q[(size_t)(qo + ((t + 1) & (d - 1))) * NC + lane] : 0.f; }
    }
    wg_barrier();

    // H2: h0 = relu(skip @ w0 + b0); readlane broadcast, 4 accumulators
    if (t_ < NV) {
      const float s0 = sskip[lane], s1 = sskip[64 + lane],
                  s2 = sskip[128 + lane], s3 = sskip[192 + lane];
      const float* __restrict__ W = w0 + t_;
      float a0 = 0.f, a1 = 0.f, a2 = 0.f, a3 = 0.f;
#pragma unroll
      for (int s = 0; s < 64; ++s) {
        a0 = fmaf(bcast(s0, s), W[(size_t)s * NV],         a0);
        a1 = fmaf(bcast(s1, s), W[(size_t)(64 + s) * NV],  a1);
        a2 = fmaf(bcast(s2, s), W[(size_t)(128 + s) * NV], a2);
        a3 = fmaf(bcast(s3, s), W[(size_t)(192 + s) * NV], a3);
      }
      sh0[t_] = fmaxf((a0 + a1) + (a2 + a3) + b0[t_], 0.f);
    }
    wg_barrier();

    // H3: logits + store + wave-level argmax (first-max semantics)
    if (t_ < NV) {
      const float h0v = sh0[lane], h1v = sh0[64 + lane],
                  h2v = sh0[128 + lane], h3v = sh0[192 + lane];
      const float* __restrict__ W = w1 + t_;
      float a0 = 0.f, a1 = 0.f, a2 = 0.f, a3 = 0.f;
#pragma unroll
      for (int s = 0; s < 64; ++s) {
        a0 = fmaf(bcast(h0v, s), W[(size_t)s * NV],         a0);
        a1 = fmaf(bcast(h1v, s), W[(size_t)(64 + s) * NV],  a1);
        a2 = fmaf(bcast(h2v, s), W[(size_t)(128 + s) * NV], a2);
        a3 = fmaf(bcast(h3v, s), W[(size_t)(192 + s) * NV], a3);
      }
      const float lg = (a0 + a1) + (a2 + a3) + b1[t_];
      out[logits_base + ((size_t)b * T + t) * NV + t_] = lg;
      float v = lg; int ix = t_;
#pragma unroll
      for (int o = 32; o > 0; o >>= 1) {
        const float ov = __shfl_down(v, o);
        const int   oi = __shfl_down(ix, o);
        if (ov > v || (ov == v && oi < ix)) { v = ov; ix = oi; }
      }
      if (lane == 0) { rv[w] = v; ri[w] = ix; }
    }
    wg_barrier();

    // H4: final argmax | wave 4: commit pop(t+1, layer 0)
    if (t_ == 0) {
      float bv = rv[0]; int bi = ri[0];
#pragma unroll
      for (int k = 1; k < 4; ++k)
        if (rv[k] > bv || (rv[k] == bv && ri[k] < bi)) { bv = rv[k]; bi = ri[k]; }
      snext = bi;
      out[(size_t)b * T + t] = (float)bi;   // samples written as float
    }
    if (w == 4) sxl[0][lane] = rP0;   // pop(t+1,1) stays in rP1 -> B(0) commit
    wg_barrier();

    // H5: embedding feedback
    if (t_ < NC) xbuf[0][t_] = emb[(size_t)snext * NC + t_];
    wg_barrier();
  }
}

extern "C" void kernel_launch(void* const* d_in, const int* in_sizes, int n_in,
                              void* d_out, int out_size, void* d_ws, size_t ws_size,
                              hipStream_t stream) {
  (void)in_sizes; (void)n_in; (void)out_size; (void)d_ws; (void)ws_size;
  wavenet_gen_kernel<<<NB, NT, 0, stream>>>(
      (const int*)d_in[0],   (const float*)d_in[1], (const float*)d_in[2],
      (const float*)d_in[3], (const float*)d_in[4], (const float*)d_in[5],
      (const float*)d_in[6], (const float*)d_in[7], (const float*)d_in[8],
      (const float*)d_in[9], (const float*)d_in[10], (const float*)d_in[11],
      (const int*)d_in[12],  (float*)d_out);
}

// Round 12
// 24037.524 us; speedup vs baseline: 2.0999x; 2.0999x over previous
//
#include <hip/hip_runtime.h>
#include <hip/hip_bf16.h>
#include <math.h>

// WaveNet autoregressive generation, MI355X, fp32 (argmax feedback forbids
// low precision; no fp32 MFMA on CDNA4 -> vector ALU kernel).
//
// R10 skeleton (12.57 ms, passed) + 4 batch elements per WG (32 WGs).
// Rationale: R10 is aggregate-L3-bandwidth-bound: 128 WGs x 4.7 MB of
// fp32 weights per step = 600 MB/step at ~6.1 TB/s sustained = 98 us/step.
// 4 elems/WG reuses each loaded weight for 4 FMAs -> aggregate demand /4.
// R7/R11 lesson: NO register weight arrays (spills); weights stream from
// global inside the dots, unroll capped to bound in-flight loads.
// lgkm-only barriers (validated correct in R11's passing run): LDS ordered,
// global loads/stores stay in flight across barriers; queue slots are
// same-thread same-address >=1 layer apart (program-order safe).

#define NL 30
#define NC 64
#define NS 256
#define NV 256
#define NB 128
#define BPW 4       // batch elements per workgroup
#define QTOT 3069   // sum of dilations: 3 * (2^10 - 1)
#define NT 320

// Per-batch dilation queues (~100.6 MB) in static device memory. Slot for
// layer l is written at step t and read at step t+d; reads gated by (t >= d)
// so stale cross-launch contents are never observed (re-poison safe).
__device__ float g_queues[(size_t)NB * QTOT * NC];

__device__ __forceinline__ void layer_params(int l, int& d, int& qo) {
  const int a = (l >= 20) ? 2 : ((l >= 10) ? 1 : 0);
  const int bb = l - a * 10;
  d = 1 << bb;
  qo = a * 1023 + (d - 1);
}

// tanh(a)*sigmoid(b) = (e^{2a}-1) / ((e^{2a}+1)*(1+e^{-b}))
__device__ __forceinline__ float gate_fast(float ha, float hb) {
  const float e2a = __expf(2.f * ha);
  const float enb = __expf(-hb);
  return (e2a - 1.f) / ((e2a + 1.f) * (1.f + enb));
}

// broadcast lane c's value across the wave (v_readlane -> SGPR operand)
__device__ __forceinline__ float bcast(float v, int c) {
  return __uint_as_float(__builtin_amdgcn_readlane(__float_as_uint(v), (unsigned)c));
}

// LDS-only barrier: orders LDS, leaves global loads/stores in flight.
__device__ __forceinline__ void wg_barrier() {
  asm volatile("s_waitcnt lgkmcnt(0)" ::: "memory");
  __builtin_amdgcn_s_barrier();
}

__global__ __launch_bounds__(NT, 1)
void wavenet_gen_kernel(const int* __restrict__ seed,
                        const float* __restrict__ emb,     // (V, C)
                        const float* __restrict__ kern,    // (L, 2, C, 2C)
                        const float* __restrict__ cbias,   // (L, 2C)
                        const float* __restrict__ resw,    // (L, C, C)
                        const float* __restrict__ resb,    // (L, C)
                        const float* __restrict__ skipw,   // (L, C, S)
                        const float* __restrict__ skipb,   // (L, S)
                        const float* __restrict__ w0,      // (S, V)
                        const float* __restrict__ b0,      // (V)
                        const float* __restrict__ w1,      // (V, V)
                        const float* __restrict__ b1,      // (V)
                        const int* __restrict__ pT,
                        float* __restrict__ out)
{
  const int b0i  = blockIdx.x * BPW;           // first batch elem of this WG
  const int t_   = threadIdx.x;
  const int T    = pT[0];
  const int lane = t_ & 63;
  const int w    = t_ >> 6;                    // wave 0..4
  const int half = w & 1;                      // conv: x_last (0) vs x (1)
  const int colA = ((w >> 1) << 6) + lane;     // conv output col 0..127

  __shared__ float xbuf[BPW][2][NC];   // layer input x (dbuf)
  __shared__ float sxl[BPW][2][NC];    // popped x_last (dbuf)
  __shared__ float hp[BPW][2][2 * NC]; // conv partials [elem][half][col]
  __shared__ float sskip[BPW][NS];
  __shared__ float sh0[BPW][NV];
  __shared__ float rv[4][BPW];
  __shared__ int   ri[4][BPW];
  __shared__ int   snext[BPW];

  float rP0[BPW], rP1[BPW];            // in-flight queue pops (wave 4)
#pragma unroll
  for (int e = 0; e < BPW; ++e) { rP0[e] = 0.f; rP1[e] = 0.f; }

  if (t_ < NC) {
#pragma unroll
    for (int e = 0; e < BPW; ++e) {
      sxl[e][0][t_] = 0.f;             // step-0 pops are zero (t=0 < d)
      sxl[e][1][t_] = 0.f;
      xbuf[e][0][t_] = emb[(size_t)seed[b0i + e] * NC + t_];
    }
  }
  // bias prefetch (scalars only; no weight arrays -> no spill)
  float rca = cbias[lane], rcb = cbias[NC + lane];
  float rsb = (w < 4) ? skipb[t_] : resb[lane];
  wg_barrier();

  const size_t qstride = (size_t)QTOT * NC;
  const size_t logits_base = (size_t)NB * (size_t)T;

  float skipacc[BPW];

  for (int t = 0; t < T; ++t) {
#pragma unroll
    for (int e = 0; e < BPW; ++e) skipacc[e] = 0.f;

    for (int i = 0; i < NL; ++i) {
      const int cb = i & 1;
      const int nx = (i + 1 < NL) ? i + 1 : 0;   // next layer (wraps)

      // ------- phase A: conv (waves 0-3) | queue push/pop (wave 4) -------
      if (w < 4) {
        float xr[BPW];
#pragma unroll
        for (int e = 0; e < BPW; ++e)
          xr[e] = half ? xbuf[e][cb][lane] : sxl[e][cb][lane];
        const float* __restrict__ W =
            kern + (size_t)(i * 2 + half) * (NC * 2 * NC) + colA;
        float a0[BPW], a1[BPW];
#pragma unroll
        for (int e = 0; e < BPW; ++e) { a0[e] = 0.f; a1[e] = 0.f; }
#pragma unroll 8
        for (int c = 0; c < NC; c += 2) {
          const float wv0 = W[(size_t)c * (2 * NC)];
          const float wv1 = W[(size_t)(c + 1) * (2 * NC)];
#pragma unroll
          for (int e = 0; e < BPW; ++e) {
            a0[e] = fmaf(bcast(xr[e], c),     wv0, a0[e]);
            a1[e] = fmaf(bcast(xr[e], c + 1), wv1, a1[e]);
          }
        }
#pragma unroll
        for (int e = 0; e < BPW; ++e) hp[e][half][colA] = a0[e] + a1[e];
      } else {
        int d, qo; layer_params(i, d, qo);
        const int j = i + 2;                     // pop 2 layers ahead
        int dj = 0, qj = 0;
        if (j < NL) layer_params(j, dj, qj);
#pragma unroll
        for (int e = 0; e < BPW; ++e) {
          float* __restrict__ q = g_queues + (size_t)(b0i + e) * qstride;
          q[(size_t)(qo + (t & (d - 1))) * NC + lane] = xbuf[e][cb][lane];
          if (j < NL) {
            float v = 0.f;
            if (t >= dj) v = q[(size_t)(qj + (t & (dj - 1))) * NC + lane];
            if (cb) rP1[e] = v; else rP0[e] = v;  // j&1 == i&1
          }
        }
      }
      wg_barrier();

      // ------- phase B: gate (all waves) + skip | res + commit pop -------
      float sgv[BPW];
#pragma unroll
      for (int e = 0; e < BPW; ++e) {
        const float ha = hp[e][0][lane] + hp[e][1][lane] + rca;
        const float hb = hp[e][0][NC + lane] + hp[e][1][NC + lane] + rcb;
        sgv[e] = gate_fast(ha, hb);              // lane c holds sg[e][c]
      }
      rca = cbias[nx * 2 * NC + lane];           // prefetch next cbias
      rcb = cbias[nx * 2 * NC + NC + lane];

      if (w < 4) {
        const float* __restrict__ SW = skipw + (size_t)i * NC * NS + t_;
        float a0[BPW];
#pragma unroll
        for (int e = 0; e < BPW; ++e) a0[e] = 0.f;
#pragma unroll 8
        for (int c = 0; c < NC; c += 2) {
          const float wv0 = SW[(size_t)c * NS];
          const float wv1 = SW[(size_t)(c + 1) * NS];
#pragma unroll
          for (int e = 0; e < BPW; ++e) {
            a0[e] = fmaf(bcast(sgv[e], c),     wv0, a0[e]);
            a0[e] = fmaf(bcast(sgv[e], c + 1), wv1, a0[e]);
          }
        }
#pragma unroll
        for (int e = 0; e < BPW; ++e) skipacc[e] += a0[e] + rsb;
        rsb = skipb[nx * NS + t_];               // prefetch next skipb
      } else {
        if (i < NL - 1) {                        // layer 29's x is dead
          const float* __restrict__ RW = resw + (size_t)i * NC * NC + lane;
          float a0[BPW];
#pragma unroll
          for (int e = 0; e < BPW; ++e) a0[e] = 0.f;
#pragma unroll 8
          for (int c = 0; c < NC; c += 2) {
            const float wv0 = RW[(size_t)c * NC];
            const float wv1 = RW[(size_t)(c + 1) * NC];
#pragma unroll
            for (int e = 0; e < BPW; ++e) {
              a0[e] = fmaf(bcast(sgv[e], c),     wv0, a0[e]);
              a0[e] = fmaf(bcast(sgv[e], c + 1), wv1, a0[e]);
            }
          }
#pragma unroll
          for (int e = 0; e < BPW; ++e) {
            xbuf[e][cb ^ 1][lane] = xbuf[e][cb][lane] + a0[e] + rsb;
            sxl[e][cb ^ 1][lane] = (cb ^ 1) ? rP1[e] : rP0[e];
          }
        }
        const int rnx = (i + 1 < NL - 1) ? i + 1 : 0;  // res cycles 0..28
        rsb = resb[rnx * NC + lane];
      }
      wg_barrier();
    }

    // ======================= output head =======================
    // H1: finalize skip | wave 4: issue pops for (t+1, layers 0 and 1)
    if (t_ < NS) {
#pragma unroll
      for (int e = 0; e < BPW; ++e) sskip[e][t_] = fmaxf(skipacc[e], 0.f);
    } else {
      int d0, qo0; layer_params(0, d0, qo0);
      int d1, qo1; layer_params(1, d1, qo1);
#pragma unroll
      for (int e = 0; e < BPW; ++e) {
        float* __restrict__ q = g_queues + (size_t)(b0i + e) * qstride;
        rP0[e] = (t + 1 >= d0) ? q[(size_t)(qo0 + ((t + 1) & (d0 - 1))) * NC + lane] : 0.f;
        rP1[e] = (t + 1 >= d1) ? q[(size_t)(qo1 + ((t + 1) & (d1 - 1))) * NC + lane] : 0.f;
      }
    }
    wg_barrier();

    // H2: h0 = relu(skip @ w0 + b0); 4 segments x 4 elems, readlane bcast
    if (t_ < NV) {
      float sv[4][BPW];
#pragma unroll
      for (int k = 0; k < 4; ++k)
#pragma unroll
        for (int e = 0; e < BPW; ++e) sv[k][e] = sskip[e][k * 64 + lane];
      const float* __restrict__ W = w0 + t_;
      float a[BPW];
#pragma unroll
      for (int e = 0; e < BPW; ++e) a[e] = 0.f;
#pragma unroll 4
      for (int s = 0; s < 64; ++s) {
        const float w0v = W[(size_t)s * NV];
        const float w1v = W[(size_t)(64 + s) * NV];
        const float w2v = W[(size_t)(128 + s) * NV];
        const float w3v = W[(size_t)(192 + s) * NV];
#pragma unroll
        for (int e = 0; e < BPW; ++e) {
          a[e] = fmaf(bcast(sv[0][e], s), w0v, a[e]);
          a[e] = fmaf(bcast(sv[1][e], s), w1v, a[e]);
          a[e] = fmaf(bcast(sv[2][e], s), w2v, a[e]);
          a[e] = fmaf(bcast(sv[3][e], s), w3v, a[e]);
        }
      }
      const float bb = b0[t_];
#pragma unroll
      for (int e = 0; e < BPW; ++e) sh0[e][t_] = fmaxf(a[e] + bb, 0.f);
    }
    wg_barrier();

    // H3: logits + store + wave-level argmax per elem (first-max semantics)
    if (t_ < NV) {
      float hv[4][BPW];
#pragma unroll
      for (int k = 0; k < 4; ++k)
#pragma unroll
        for (int e = 0; e < BPW; ++e) hv[k][e] = sh0[e][k * 64 + lane];
      const float* __restrict__ W = w1 + t_;
      float a[BPW];
#pragma unroll
      for (int e = 0; e < BPW; ++e) a[e] = 0.f;
#pragma unroll 4
      for (int s = 0; s < 64; ++s) {
        const float w0v = W[(size_t)s * NV];
        const float w1v = W[(size_t)(64 + s) * NV];
        const float w2v = W[(size_t)(128 + s) * NV];
        const float w3v = W[(size_t)(192 + s) * NV];
#pragma unroll
        for (int e = 0; e < BPW; ++e) {
          a[e] = fmaf(bcast(hv[0][e], s), w0v, a[e]);
          a[e] = fmaf(bcast(hv[1][e], s), w1v, a[e]);
          a[e] = fmaf(bcast(hv[2][e], s), w2v, a[e]);
          a[e] = fmaf(bcast(hv[3][e], s), w3v, a[e]);
        }
      }
      const float bb = b1[t_];
#pragma unroll
      for (int e = 0; e < BPW; ++e) {
        const float lg = a[e] + bb;
        out[logits_base + ((size_t)(b0i + e) * T + t) * NV + t_] = lg;
        float v = lg; int ix = t_;
#pragma unroll
        for (int o = 32; o > 0; o >>= 1) {
          const float ov = __shfl_down(v, o);
          const int   oi = __shfl_down(ix, o);
          if (ov > v || (ov == v && oi < ix)) { v = ov; ix = oi; }
        }
        if (lane == 0) { rv[w][e] = v; ri[w][e] = ix; }
      }
    }
    wg_barrier();

    // H4: final argmax | wave 4: commit pop(t+1, layer 0)
    if (t_ == 0) {
#pragma unroll
      for (int e = 0; e < BPW; ++e) {
        float bv = rv[0][e]; int bi = ri[0][e];
#pragma unroll
        for (int k = 1; k < 4; ++k)
          if (rv[k][e] > bv || (rv[k][e] == bv && ri[k][e] < bi)) { bv = rv[k][e]; bi = ri[k][e]; }
        snext[e] = bi;
        out[(size_t)(b0i + e) * T + t] = (float)bi;  // samples as float
      }
    }
    if (w == 4) {
#pragma unroll
      for (int e = 0; e < BPW; ++e) sxl[e][0][lane] = rP0[e];
      // pop(t+1, layer 1) stays in rP1[e] -> committed at B(0) next step
    }
    wg_barrier();

    // H5: embedding feedback
    if (t_ < NC) {
#pragma unroll
      for (int e = 0; e < BPW; ++e)
        xbuf[e][0][t_] = emb[(size_t)snext[e] * NC + t_];
    }
    wg_barrier();
  }
}

extern "C" void kernel_launch(void* const* d_in, const int* in_sizes, int n_in,
                              void* d_out, int out_size, void* d_ws, size_t ws_size,
                              hipStream_t stream) {
  (void)in_sizes; (void)n_in; (void)out_size; (void)d_ws; (void)ws_size;
  wavenet_gen_kernel<<<NB / BPW, NT, 0, stream>>>(
      (const int*)d_in[0],   (const float*)d_in[1], (const float*)d_in[2],
      (const float*)d_in[3], (const float*)d_in[4], (const float*)d_in[5],
      (const float*)d_in[6], (const float*)d_in[7], (const float*)d_in[8],
      (const float*)d_in[9], (const float*)d_in[10], (const float*)d_in[11],
      (const int*)d_in[12],  (float*)d_out);
}